// Round 2
// baseline (518.206 us; speedup 1.0000x reference)
//
#include <hip/hip_runtime.h>
#include <stdint.h>

// HalutMatmul forward, fp32 in/out, gfx950.
// N=32768, D=512, C=64, K=16, M=512, DEPTH=4, NODES=15.
// R2: occupancy attack (counters: all pipes <8%, occupancy 17% -> latency-bound).
// k0_prep: fused A->At hi/lo planes + L->bf16 + cnt=0 (one dispatch).
// k1 : P=I@A (hi/lo split bf16 MFMA) + tree codes. Pl LDS epilogue ELIMINATED:
//      in-register 4x4 lane transpose (shfl_xor) of MFMA frags feeds the descent.
//      LDS = 40960B staging only -> 4 blocks/CU (16 waves, was 8). m97 2-barrier loop.
// k1b: fp64 rescue of flagged (n,c) codes (unchanged).
// k2 : out = onehot(codes)@L^T. BK 128->64, LDS 24.5KB, launch_bounds(256,4)
//      -> 4 blocks/CU (was 3 in R0, 2 in R1).

#define DDIM 512
#define CD4 256
#define CKDIM 1024
#define MOUT 512
#define NODES 15
#define CAP (1u << 20)

typedef unsigned short u16;
typedef unsigned int u32;
typedef __attribute__((ext_vector_type(8))) __bf16 bf16x8;
typedef __attribute__((ext_vector_type(4))) float f32x4;
typedef __attribute__((ext_vector_type(4))) u32 u32x4;

__device__ __forceinline__ void gld_lds16(const void* g, void* l) {
  __builtin_amdgcn_global_load_lds(
      (const __attribute__((address_space(1))) void*)g,
      (__attribute__((address_space(3))) void*)l, 16, 0, 0);
}
__device__ __forceinline__ float bf2f(u16 u) {
  uint32_t x = ((uint32_t)u) << 16; return __builtin_bit_cast(float, x);
}
__device__ __forceinline__ u16 f2bf(float f) {  // RNE
  uint32_t x = __builtin_bit_cast(uint32_t, f);
  return (u16)((x + 0x7FFFu + ((x >> 16) & 1u)) >> 16);
}

// ---- k0_prep: fused preprocessing, one dispatch ----
// blocks 0..31: A (512x256 f32) -> At hi/lo bf16 planes (256x512), LDS transpose
// blocks 32..543: L (512x1024 f32) -> bf16 plane; block 32 t0 zeroes flagcnt
__global__ __launch_bounds__(256) void k0_prep(const float* __restrict__ Ag,
                                               u16* __restrict__ Ath,
                                               u16* __restrict__ Atl,
                                               const float* __restrict__ Lg,
                                               u16* __restrict__ Lb,
                                               u32* __restrict__ flagcnt) {
  const int bx = blockIdx.x, t = threadIdx.x;
  if (bx < 32) {
    __shared__ float Tl[64][65];  // +1 pad: conflict-free column reads
    const int cx = bx & 3, ky = bx >> 2;
    const int lane = t & 63, w = t >> 6;
#pragma unroll
    for (int rr = 0; rr < 16; ++rr) {  // read: rows coalesced over lanes
      int r = w * 16 + rr;
      Tl[r][lane] = Ag[(size_t)(ky * 64 + r) * CD4 + cx * 64 + lane];
    }
    __syncthreads();
#pragma unroll
    for (int rr = 0; rr < 16; ++rr) {  // write: k coalesced over lanes
      int c = w * 16 + rr;
      float x = Tl[lane][c];
      u16 h = f2bf(x);
      u16 l = f2bf(x - bf2f(h));
      size_t o = (size_t)(cx * 64 + c) * DDIM + ky * 64 + lane;
      Ath[o] = h;
      Atl[o] = l;
    }
  } else {
    if (bx == 32 && t == 0) *flagcnt = 0;
    int i = ((bx - 32) * 256 + t) * 4;
    f32x4 v = *(const f32x4*)(Lg + i);
    u32 lo = (u32)f2bf(v[0]) | ((u32)f2bf(v[1]) << 16);
    u32 hi = (u32)f2bf(v[2]) | ((u32)f2bf(v[3]) << 16);
    *(u32*)(Lb + i) = lo;
    *(u32*)(Lb + i + 2) = hi;
  }
}

// ---- k1: coarse P (hi/lo split MFMA) + tree codes + flags ----
// tile 64 I-rows x 256 P-cols (all 64 codebooks). grid 512 (nb only).
// LDS 40KB single-buffer staging (If 8KB + Bt 32KB) -> 4 blocks/CU.
// Epilogue: per-frag 4x4 lane transpose (shfl_xor) -> descent in registers;
// T staged into If region, codes assembled in Bt region, coalesced store.
__global__ __launch_bounds__(256, 4) void k1_p_codes(
    const float* __restrict__ Ig, const u16* __restrict__ Ath,
    const float* __restrict__ Tg,
    uint8_t* __restrict__ codes, u32* __restrict__ flagcnt,
    u32* __restrict__ flaglist) {
  __shared__ __align__(16) char smem[40960];
  float* If = (float*)smem;        // 8KB: [64 rows][8 slots]x16B, slot s holds g=s^(r&7)
  u16* Bt = (u16*)(smem + 8192);   // 32KB: [256 rows][8 slots]; g<4 hi plane, g>=4 lo

  const int t = threadIdx.x, nb = blockIdx.x;
  const int lane = t & 63, wave = t >> 6, quad = lane >> 4, l16 = lane & 15;
  const int wr = wave >> 1, wc = wave & 1;  // 2x2 waves over 64x256

  f32x4 acc[2][8] = {};

  for (int kb = 0; kb < 16; ++kb) {
    __syncthreads();  // prev iter's ds_reads retired before restage
    // I tile: 64 rows x 8 chunk-slots = 512 chunks = 2*256
#pragma unroll
    for (int q = 0; q < 2; ++q) {
      int cid = t + q * 256, r = cid >> 3, s = cid & 7, g = s ^ (r & 7);
      gld_lds16(Ig + (size_t)(nb * 64 + r) * DDIM + kb * 32 + g * 4, If + cid * 4);
    }
    // B tile: 256 At-rows x 8 slots; g<4 -> hi plane (k-chunk g), g>=4 -> lo (g-4)
#pragma unroll
    for (int q = 0; q < 8; ++q) {
      int cid = t + q * 256, r = cid >> 3, s = cid & 7, g = s ^ (r & 7);
      gld_lds16(Ath + (size_t)(g >> 2) * (256 * DDIM) +
                    (size_t)r * DDIM + kb * 32 + (g & 3) * 8,
                Bt + cid * 8);
    }
    __syncthreads();  // staged data visible (vmcnt(0) drained by compiler)

    bf16x8 ah[2], al[2], bh[8], bl[8];
#pragma unroll
    for (int i = 0; i < 2; ++i) {
      int ra = wr * 32 + i * 16 + l16;
      int s0 = ra * 8 + ((quad * 2) ^ (ra & 7));
      int s1 = ra * 8 + ((quad * 2 + 1) ^ (ra & 7));
      f32x4 c0 = *(const f32x4*)(If + s0 * 4);
      f32x4 c1 = *(const f32x4*)(If + s1 * 4);
      float xs[8] = {c0[0], c0[1], c0[2], c0[3], c1[0], c1[1], c1[2], c1[3]};
      u32 hw[4], lw[4];
#pragma unroll
      for (int p = 0; p < 4; ++p) {  // truncation split: hi = top16 bits, lo = x - hi
        u32 u0 = __builtin_bit_cast(u32, xs[2 * p]);
        u32 u1 = __builtin_bit_cast(u32, xs[2 * p + 1]);
        hw[p] = __builtin_amdgcn_perm(u1, u0, 0x07060302);
        float h0 = __builtin_bit_cast(float, u0 & 0xFFFF0000u);
        float h1 = __builtin_bit_cast(float, u1 & 0xFFFF0000u);
        u32 l0 = __builtin_bit_cast(u32, xs[2 * p] - h0);
        u32 l1 = __builtin_bit_cast(u32, xs[2 * p + 1] - h1);
        lw[p] = __builtin_amdgcn_perm(l1, l0, 0x07060302);
      }
      ah[i] = __builtin_bit_cast(bf16x8, (u32x4){hw[0], hw[1], hw[2], hw[3]});
      al[i] = __builtin_bit_cast(bf16x8, (u32x4){lw[0], lw[1], lw[2], lw[3]});
    }
#pragma unroll
    for (int j = 0; j < 8; ++j) {
      int rb = wc * 128 + j * 16 + l16;
      int sh = quad ^ (rb & 7), sl = (4 + quad) ^ (rb & 7);
      bh[j] = *(const bf16x8*)(Bt + (rb * 8 + sh) * 8);
      bl[j] = *(const bf16x8*)(Bt + (rb * 8 + sl) * 8);
    }
    __builtin_amdgcn_s_setprio(1);
#pragma unroll
    for (int i = 0; i < 2; ++i)
#pragma unroll
      for (int j = 0; j < 8; ++j) {
        acc[i][j] = __builtin_amdgcn_mfma_f32_16x16x32_bf16(ah[i], bh[j], acc[i][j], 0, 0, 0);
        acc[i][j] = __builtin_amdgcn_mfma_f32_16x16x32_bf16(ah[i], bl[j], acc[i][j], 0, 0, 0);
        acc[i][j] = __builtin_amdgcn_mfma_f32_16x16x32_bf16(al[i], bh[j], acc[i][j], 0, 0, 0);
      }
    __builtin_amdgcn_s_setprio(0);
  }

  __syncthreads();  // last iter's LDS reads done; reuse smem
  float* Tl = (float*)smem;               // 3.84KB thresholds in If region
  uint8_t* codes_lds = (uint8_t*)(smem + 8192);  // [64 rows][64 c] in Bt region
  if (t < 240) *(f32x4*)(Tl + t * 4) = *(const f32x4*)(Tg + t * 4);
  __syncthreads();

  // Epilogue: MFMA C layout per lane = 4 rows (regs) x 1 col (l16).
  // col = c*4 + level, so lanes 4c..4c+3 of a quad hold levels 0..3 of codebook c.
  // 4x4 lane transpose (xor1, xor2) -> lane m = l16&3 holds row m's 4 levels.
#pragma unroll
  for (int i = 0; i < 2; ++i)
#pragma unroll
    for (int j = 0; j < 8; ++j) {
      f32x4 v = acc[i][j];
      {
        float x = (l16 & 1) ? v[0] : v[1];
        float y = (l16 & 1) ? v[2] : v[3];
        x = __shfl_xor(x, 1);
        y = __shfl_xor(y, 1);
        if (l16 & 1) { v[0] = x; v[2] = y; } else { v[1] = x; v[3] = y; }
        float p = (l16 & 2) ? v[0] : v[2];
        float q = (l16 & 2) ? v[1] : v[3];
        p = __shfl_xor(p, 2);
        q = __shfl_xor(q, 2);
        if (l16 & 2) { v[0] = p; v[1] = q; } else { v[2] = p; v[3] = q; }
      }
      int row = wr * 32 + i * 16 + quad * 4 + (l16 & 3);
      int cg = wc * 32 + j * 4 + (l16 >> 2);
      const float* Tc = Tl + cg * NODES;
      int node = 0, k = 0;
      float mm = 1e30f;
#pragma unroll
      for (int l = 0; l < 4; ++l) {
        float h = v[l] - Tc[node];
        mm = fminf(mm, __builtin_fabsf(h));
        int bit = h > 0.0f ? 1 : 0;
        k = (k << 1) | bit;
        node = 2 * node + 1 + bit;
      }
      codes_lds[row * 64 + cg] = (uint8_t)k;
      if (mm < 2e-3f) {  // coarse error ~1e-4 << tau: unflagged codes are exact
        u32 pos = atomicAdd(flagcnt, 1u);
        if (pos < CAP) flaglist[pos] = ((u32)(nb * 64 + row) << 6) | (u32)cg;
      }
    }
  __syncthreads();
  // coalesced codes write: 256 threads x 16B = 4KB tile
  *(u32x4*)(codes + (size_t)nb * 4096 + t * 16) =
      *(const u32x4*)(codes_lds + t * 16);
}

// ---- k1b: fp64 rescue of flagged codes ----
__global__ void k1b_rescue(const float* __restrict__ Ig, const float* __restrict__ Ag,
                           const float* __restrict__ Tg, const u32* __restrict__ cnt,
                           const u32* __restrict__ list, uint8_t* __restrict__ codes) {
  u32 total = *cnt;
  if (total > CAP) total = CAP;
  for (u32 e = blockIdx.x * blockDim.x + threadIdx.x; e < total;
       e += gridDim.x * blockDim.x) {
    u32 v = list[e];
    int n = v >> 6, c = v & 63;
    double p[4] = {0.0, 0.0, 0.0, 0.0};
    const float* Ir = Ig + (size_t)n * DDIM;
    const float* Ac = Ag + c * 4;
    for (int d = 0; d < DDIM; ++d) {
      double iv = (double)Ir[d];
      f32x4 a = *(const f32x4*)(Ac + (size_t)d * CD4);
      p[0] += iv * (double)a[0]; p[1] += iv * (double)a[1];
      p[2] += iv * (double)a[2]; p[3] += iv * (double)a[3];
    }
    const float* Tc = Tg + c * NODES;
    int node = 0, k = 0;
    for (int l = 0; l < 4; ++l) {
      int bit = p[l] > (double)Tc[node] ? 1 : 0;
      k = (k << 1) | bit;
      node = 2 * node + 1 + bit;
    }
    codes[(size_t)n * 64 + c] = (uint8_t)k;
  }
}

// ---- k2: out = onehot(codes) @ L^T, fp32 out. BK=64, 4 blocks/CU ----
__global__ __launch_bounds__(256, 4) void k2_out(
    const uint8_t* __restrict__ codes, const u16* __restrict__ Lb,
    float* __restrict__ Og) {
  __shared__ __align__(16) u16 Ltile[128 * 64];       // 16KB [m-row][8 slots], XOR
  __shared__ __align__(16) uint8_t codesT[64 * 128];  // [c][n] 8KB
  __shared__ __align__(16) u16 lut[32 * 8];

  const int t = threadIdx.x, mb = blockIdx.x, nb = blockIdx.y;
  const int lane = t & 63, wave = t >> 6, quad = lane >> 4, l16 = lane & 15;
  const int wr = wave >> 1, wc = wave & 1;

  if (t < 32) {  // A-frag LUT: entry (h,v): frag[j] = (v == h*8+j)
    int h = t >> 4, v = t & 15;
#pragma unroll
    for (int j = 0; j < 8; ++j)
      lut[t * 8 + j] = (v == h * 8 + j) ? (u16)0x3F80 : (u16)0;
  }
  {  // codes -> [c][n] transposed in LDS
    int n = t >> 1, part = t & 1;
    const u32* src = (const u32*)(codes + (size_t)(nb * 128 + n) * 64 + part * 32);
#pragma unroll
    for (int i = 0; i < 8; ++i) {
      u32 w = src[i];
      int c4 = part * 32 + i * 4;
      codesT[(c4 + 0) * 128 + n] = (uint8_t)(w & 0xff);
      codesT[(c4 + 1) * 128 + n] = (uint8_t)((w >> 8) & 0xff);
      codesT[(c4 + 2) * 128 + n] = (uint8_t)((w >> 16) & 0xff);
      codesT[(c4 + 3) * 128 + n] = (uint8_t)((w >> 24) & 0xff);
    }
  }

  f32x4 acc[4][4] = {};

  for (int kb = 0; kb < 16; ++kb) {
    __syncthreads();  // first iter: codesT/lut visible; later: prev reads retired
#pragma unroll
    for (int q = 0; q < 4; ++q) {  // 128 rows x 8 slots = 1024 chunks of 16B
      int cid = t + q * 256, r = cid >> 3, s = cid & 7, g = s ^ (r & 7);
      gld_lds16(Lb + (size_t)(mb * 128 + r) * CKDIM + kb * 64 + g * 8,
                Ltile + cid * 8);
    }
    __syncthreads();

#pragma unroll
    for (int ks = 0; ks < 2; ++ks) {
      const int c0 = kb * 4 + ks * 2 + (quad >> 1);
      const int h = quad & 1;
      bf16x8 a[4], b[4];
#pragma unroll
      for (int i = 0; i < 4; ++i) {
        int row = wr * 64 + i * 16 + l16;
        int v = codesT[c0 * 128 + row] & 15;  // defensive mask
        a[i] = *(const bf16x8*)(lut + (h * 16 + v) * 8);
      }
#pragma unroll
      for (int j = 0; j < 4; ++j) {
        int rm = wc * 64 + j * 16 + l16;
        int slot = (ks * 4 + quad) ^ (rm & 7);
        b[j] = *(const bf16x8*)(Ltile + rm * 64 + slot * 8);
      }
      __builtin_amdgcn_s_setprio(1);
#pragma unroll
      for (int i = 0; i < 4; ++i)
#pragma unroll
        for (int j = 0; j < 4; ++j)
          acc[i][j] = __builtin_amdgcn_mfma_f32_16x16x32_bf16(a[i], b[j], acc[i][j], 0, 0, 0);
      __builtin_amdgcn_s_setprio(0);
    }
  }

#pragma unroll
  for (int i = 0; i < 4; ++i)
#pragma unroll
    for (int j = 0; j < 4; ++j) {
      int row = nb * 128 + wr * 64 + i * 16 + quad * 4;
      int col = mb * 128 + wc * 64 + j * 16 + l16;
#pragma unroll
      for (int r = 0; r < 4; ++r)
        Og[(size_t)(row + r) * MOUT + col] = acc[i][j][r];
    }
}

extern "C" void kernel_launch(void* const* d_in, const int* in_sizes, int n_in,
                              void* d_out, int out_size, void* d_ws, size_t ws_size,
                              hipStream_t stream) {
  // inputs (all float32): I (N,512), T (960), L (512,64,16), A (512,256), S, B
  const float* Ig = (const float*)d_in[0];
  const float* Tg = (const float*)d_in[1];
  const float* Lg = (const float*)d_in[2];
  const float* Ag = (const float*)d_in[3];
  float* Og = (float*)d_out;

  char* ws = (char*)d_ws;
  u32* cnt = (u32*)ws;                                 // 4B @ 0
  u32* list = (u32*)(ws + 4096);                       // 4MB flag list
  uint8_t* codes = (uint8_t*)(ws + (8u << 20));        // 2MB @ 8MB
  u16* Ath = (u16*)(ws + (10u << 20));                 // 256KB @ 10MB
  u16* Atl = Ath + 256 * DDIM;                         // 256KB, ADJACENT (k1 relies on it)
  u16* Lbf = (u16*)(ws + (10u << 20) + (512u << 10));  // 1MB

  k0_prep<<<dim3(544), dim3(256), 0, stream>>>(Ag, Ath, Atl, Lg, Lbf, cnt);
  k1_p_codes<<<dim3(512), dim3(256), 0, stream>>>(Ig, Ath, Tg, codes, cnt, list);
  k1b_rescue<<<dim3(256), dim3(256), 0, stream>>>(Ig, Ag, Tg, cnt, list, codes);
  k2_out<<<dim3(4, 256), dim3(256), 0, stream>>>(codes, Lbf, Og);
}

// Round 3
// 248.953 us; speedup vs baseline: 2.0815x; 2.0815x over previous
//
#include <hip/hip_runtime.h>
#include <stdint.h>

// HalutMatmul forward, fp32 in/out, gfx950.
// N=32768, D=512, C=64, K=16, M=512, DEPTH=4, NODES=15.
// R3: (a) un-spill k1 (launch_bounds(256,3): R2's (256,4) forced VGPR=64 -> 430MB
//     scratch traffic, 287us). (b) k1 flag path: per-wave ballot compaction + ONE
//     block atomic (was ~12k same-address device atomics). (c) k1b: wave-per-entry
//     (was thread-per-entry 512-dim scalar latency chain). (d) k2: (256,3).
// k0_prep: fused A->At hi/lo planes + L->bf16 + cnt=0 (one dispatch).

#define DDIM 512
#define CD4 256
#define CKDIM 1024
#define MOUT 512
#define NODES 15
#define CAP (1u << 20)

typedef unsigned short u16;
typedef unsigned int u32;
typedef __attribute__((ext_vector_type(8))) __bf16 bf16x8;
typedef __attribute__((ext_vector_type(4))) float f32x4;
typedef __attribute__((ext_vector_type(4))) u32 u32x4;

__device__ __forceinline__ void gld_lds16(const void* g, void* l) {
  __builtin_amdgcn_global_load_lds(
      (const __attribute__((address_space(1))) void*)g,
      (__attribute__((address_space(3))) void*)l, 16, 0, 0);
}
__device__ __forceinline__ float bf2f(u16 u) {
  uint32_t x = ((uint32_t)u) << 16; return __builtin_bit_cast(float, x);
}
__device__ __forceinline__ u16 f2bf(float f) {  // RNE
  uint32_t x = __builtin_bit_cast(uint32_t, f);
  return (u16)((x + 0x7FFFu + ((x >> 16) & 1u)) >> 16);
}

// ---- k0_prep: fused preprocessing, one dispatch ----
// blocks 0..31: A (512x256 f32) -> At hi/lo bf16 planes (256x512), LDS transpose
// blocks 32..543: L (512x1024 f32) -> bf16 plane; block 32 t0 zeroes flagcnt
__global__ __launch_bounds__(256) void k0_prep(const float* __restrict__ Ag,
                                               u16* __restrict__ Ath,
                                               u16* __restrict__ Atl,
                                               const float* __restrict__ Lg,
                                               u16* __restrict__ Lb,
                                               u32* __restrict__ flagcnt) {
  const int bx = blockIdx.x, t = threadIdx.x;
  if (bx < 32) {
    __shared__ float Tl[64][65];  // +1 pad: conflict-free column reads
    const int cx = bx & 3, ky = bx >> 2;
    const int lane = t & 63, w = t >> 6;
#pragma unroll
    for (int rr = 0; rr < 16; ++rr) {  // read: rows coalesced over lanes
      int r = w * 16 + rr;
      Tl[r][lane] = Ag[(size_t)(ky * 64 + r) * CD4 + cx * 64 + lane];
    }
    __syncthreads();
#pragma unroll
    for (int rr = 0; rr < 16; ++rr) {  // write: k coalesced over lanes
      int c = w * 16 + rr;
      float x = Tl[lane][c];
      u16 h = f2bf(x);
      u16 l = f2bf(x - bf2f(h));
      size_t o = (size_t)(cx * 64 + c) * DDIM + ky * 64 + lane;
      Ath[o] = h;
      Atl[o] = l;
    }
  } else {
    if (bx == 32 && t == 0) *flagcnt = 0;
    int i = ((bx - 32) * 256 + t) * 4;
    f32x4 v = *(const f32x4*)(Lg + i);
    u32 lo = (u32)f2bf(v[0]) | ((u32)f2bf(v[1]) << 16);
    u32 hi = (u32)f2bf(v[2]) | ((u32)f2bf(v[3]) << 16);
    *(u32*)(Lb + i) = lo;
    *(u32*)(Lb + i + 2) = hi;
  }
}

// ---- k1: coarse P (hi/lo split MFMA) + tree codes + flags ----
// tile 64 I-rows x 256 P-cols (all 64 codebooks). grid 512 (nb only).
// LDS 40KB single-buffer staging (If 8KB + Bt 32KB); (256,3) -> 3 blocks/CU.
// Epilogue: per-frag 4x4 lane transpose (shfl_xor) -> descent in registers;
// flags: ballot-compacted per wave in LDS, ONE atomicAdd per block, coalesced flush.
__global__ __launch_bounds__(256, 3) void k1_p_codes(
    const float* __restrict__ Ig, const u16* __restrict__ Ath,
    const float* __restrict__ Tg,
    uint8_t* __restrict__ codes, u32* __restrict__ flagcnt,
    u32* __restrict__ flaglist) {
  __shared__ __align__(16) char smem[40960];
  float* If = (float*)smem;        // 8KB: [64 rows][8 slots]x16B, slot s holds g=s^(r&7)
  u16* Bt = (u16*)(smem + 8192);   // 32KB: [256 rows][8 slots]; g<4 hi plane, g>=4 lo

  const int t = threadIdx.x, nb = blockIdx.x;
  const int lane = t & 63, wave = t >> 6, quad = lane >> 4, l16 = lane & 15;
  const int wr = wave >> 1, wc = wave & 1;  // 2x2 waves over 64x256

  f32x4 acc[2][8] = {};

  for (int kb = 0; kb < 16; ++kb) {
    __syncthreads();  // prev iter's ds_reads retired before restage
    // I tile: 64 rows x 8 chunk-slots = 512 chunks = 2*256
#pragma unroll
    for (int q = 0; q < 2; ++q) {
      int cid = t + q * 256, r = cid >> 3, s = cid & 7, g = s ^ (r & 7);
      gld_lds16(Ig + (size_t)(nb * 64 + r) * DDIM + kb * 32 + g * 4, If + cid * 4);
    }
    // B tile: 256 At-rows x 8 slots; g<4 -> hi plane (k-chunk g), g>=4 -> lo (g-4)
#pragma unroll
    for (int q = 0; q < 8; ++q) {
      int cid = t + q * 256, r = cid >> 3, s = cid & 7, g = s ^ (r & 7);
      gld_lds16(Ath + (size_t)(g >> 2) * (256 * DDIM) +
                    (size_t)r * DDIM + kb * 32 + (g & 3) * 8,
                Bt + cid * 8);
    }
    __syncthreads();  // staged data visible (vmcnt(0) drained by compiler)

    bf16x8 ah[2], al[2], bh[8], bl[8];
#pragma unroll
    for (int i = 0; i < 2; ++i) {
      int ra = wr * 32 + i * 16 + l16;
      int s0 = ra * 8 + ((quad * 2) ^ (ra & 7));
      int s1 = ra * 8 + ((quad * 2 + 1) ^ (ra & 7));
      f32x4 c0 = *(const f32x4*)(If + s0 * 4);
      f32x4 c1 = *(const f32x4*)(If + s1 * 4);
      float xs[8] = {c0[0], c0[1], c0[2], c0[3], c1[0], c1[1], c1[2], c1[3]};
      u32 hw[4], lw[4];
#pragma unroll
      for (int p = 0; p < 4; ++p) {  // truncation split: hi = top16 bits, lo = x - hi
        u32 u0 = __builtin_bit_cast(u32, xs[2 * p]);
        u32 u1 = __builtin_bit_cast(u32, xs[2 * p + 1]);
        hw[p] = __builtin_amdgcn_perm(u1, u0, 0x07060302);
        float h0 = __builtin_bit_cast(float, u0 & 0xFFFF0000u);
        float h1 = __builtin_bit_cast(float, u1 & 0xFFFF0000u);
        u32 l0 = __builtin_bit_cast(u32, xs[2 * p] - h0);
        u32 l1 = __builtin_bit_cast(u32, xs[2 * p + 1] - h1);
        lw[p] = __builtin_amdgcn_perm(l1, l0, 0x07060302);
      }
      ah[i] = __builtin_bit_cast(bf16x8, (u32x4){hw[0], hw[1], hw[2], hw[3]});
      al[i] = __builtin_bit_cast(bf16x8, (u32x4){lw[0], lw[1], lw[2], lw[3]});
    }
#pragma unroll
    for (int j = 0; j < 8; ++j) {
      int rb = wc * 128 + j * 16 + l16;
      int sh = quad ^ (rb & 7), sl = (4 + quad) ^ (rb & 7);
      bh[j] = *(const bf16x8*)(Bt + (rb * 8 + sh) * 8);
      bl[j] = *(const bf16x8*)(Bt + (rb * 8 + sl) * 8);
    }
    __builtin_amdgcn_s_setprio(1);
#pragma unroll
    for (int i = 0; i < 2; ++i)
#pragma unroll
      for (int j = 0; j < 8; ++j) {
        acc[i][j] = __builtin_amdgcn_mfma_f32_16x16x32_bf16(ah[i], bh[j], acc[i][j], 0, 0, 0);
        acc[i][j] = __builtin_amdgcn_mfma_f32_16x16x32_bf16(ah[i], bl[j], acc[i][j], 0, 0, 0);
        acc[i][j] = __builtin_amdgcn_mfma_f32_16x16x32_bf16(al[i], bh[j], acc[i][j], 0, 0, 0);
      }
    __builtin_amdgcn_s_setprio(0);
  }

  __syncthreads();  // last iter's LDS reads done; reuse smem
  float* Tl = (float*)smem;                        // 3.84KB thresholds
  uint8_t* codes_lds = (uint8_t*)(smem + 4096);    // [64 rows][64 c] 4KB
  u32* flagbuf = (u32*)(smem + 8192);              // [4 waves][1024] 16KB
  u32* fmeta = (u32*)(smem + 8192 + 16384);        // wave counts + base
  if (t < 240) *(f32x4*)(Tl + t * 4) = *(const f32x4*)(Tg + t * 4);
  __syncthreads();

  // Epilogue: MFMA C layout per lane = 4 rows (regs) x 1 col (l16).
  // col = c*4 + level, so lanes 4c..4c+3 of a quad hold levels 0..3 of codebook c.
  // 4x4 lane transpose (xor1, xor2) -> lane m = l16&3 holds row m's 4 levels.
  u32 wcnt = 0;  // wave-uniform running flag count
#pragma unroll
  for (int i = 0; i < 2; ++i)
#pragma unroll
    for (int j = 0; j < 8; ++j) {
      f32x4 v = acc[i][j];
      {
        float x = (l16 & 1) ? v[0] : v[1];
        float y = (l16 & 1) ? v[2] : v[3];
        x = __shfl_xor(x, 1);
        y = __shfl_xor(y, 1);
        if (l16 & 1) { v[0] = x; v[2] = y; } else { v[1] = x; v[3] = y; }
        float p = (l16 & 2) ? v[0] : v[2];
        float q = (l16 & 2) ? v[1] : v[3];
        p = __shfl_xor(p, 2);
        q = __shfl_xor(q, 2);
        if (l16 & 2) { v[0] = p; v[1] = q; } else { v[2] = p; v[3] = q; }
      }
      int row = wr * 32 + i * 16 + quad * 4 + (l16 & 3);
      int cg = wc * 32 + j * 4 + (l16 >> 2);
      const float* Tc = Tl + cg * NODES;
      int node = 0, k = 0;
      float mm = 1e30f;
#pragma unroll
      for (int l = 0; l < 4; ++l) {
        float h = v[l] - Tc[node];
        mm = fminf(mm, __builtin_fabsf(h));
        int bit = h > 0.0f ? 1 : 0;
        k = (k << 1) | bit;
        node = 2 * node + 1 + bit;
      }
      codes_lds[row * 64 + cg] = (uint8_t)k;
      // coarse error ~1e-4 << tau: unflagged codes are exact. Ballot-compact.
      bool fl = mm < 2e-3f;
      unsigned long long bm = __ballot(fl);
      if (bm) {
        if (fl) {
          int rank = __popcll(bm & ((1ull << lane) - 1ull));
          flagbuf[wave * 1024 + wcnt + rank] =
              ((u32)(nb * 64 + row) << 6) | (u32)cg;
        }
        wcnt += (u32)__popcll(bm);
      }
    }
  if (lane == 0) fmeta[wave] = wcnt;
  __syncthreads();
  {
    u32 c0 = fmeta[0], c1 = fmeta[1], c2 = fmeta[2], c3 = fmeta[3];
    u32 total = c0 + c1 + c2 + c3;
    if (t == 0 && total) fmeta[4] = atomicAdd(flagcnt, total);
    // coalesced codes write: 256 threads x 16B = 4KB tile
    *(u32x4*)(codes + (size_t)nb * 4096 + t * 16) =
        *(const u32x4*)(codes_lds + t * 16);
    __syncthreads();
    if (total) {
      u32 base = fmeta[4];
      u32 pre = (wave > 0 ? c0 : 0) + (wave > 1 ? c1 : 0) + (wave > 2 ? c2 : 0);
      u32 mycnt = fmeta[wave];
      for (u32 i2 = (u32)lane; i2 < mycnt; i2 += 64) {
        u32 pos = base + pre + i2;
        if (pos < CAP) flaglist[pos] = flagbuf[wave * 1024 + i2];
      }
    }
  }
}

// ---- k1b: fp64 rescue, one WAVE per flagged entry ----
// lanes split the 512 dims (coalesced I reads), butterfly fp64 reduce, lane 0 descends.
__global__ __launch_bounds__(256) void k1b_rescue(
    const float* __restrict__ Ig, const float* __restrict__ Ag,
    const float* __restrict__ Tg, const u32* __restrict__ cnt,
    const u32* __restrict__ list, uint8_t* __restrict__ codes) {
  u32 total = *cnt;
  if (total > CAP) total = CAP;
  const int lane = threadIdx.x & 63;
  const u32 wid = (u32)((blockIdx.x * blockDim.x + threadIdx.x) >> 6);
  const u32 nw = (u32)((gridDim.x * blockDim.x) >> 6);
  for (u32 e = wid; e < total; e += nw) {
    u32 v = list[e];
    int n = v >> 6, c = v & 63;
    const float* Ir = Ig + (size_t)n * DDIM;
    const float* Ac = Ag + c * 4;
    double p0 = 0.0, p1 = 0.0, p2 = 0.0, p3 = 0.0;
#pragma unroll
    for (int u = 0; u < 8; ++u) {
      int d = u * 64 + lane;
      double iv = (double)Ir[d];
      f32x4 a = *(const f32x4*)(Ac + (size_t)d * CD4);
      p0 += iv * (double)a[0]; p1 += iv * (double)a[1];
      p2 += iv * (double)a[2]; p3 += iv * (double)a[3];
    }
#pragma unroll
    for (int off = 32; off; off >>= 1) {
      p0 += __shfl_xor(p0, off);
      p1 += __shfl_xor(p1, off);
      p2 += __shfl_xor(p2, off);
      p3 += __shfl_xor(p3, off);
    }
    if (lane == 0) {
      double p[4] = {p0, p1, p2, p3};
      const float* Tc = Tg + c * NODES;
      int node = 0, k = 0;
      for (int l = 0; l < 4; ++l) {
        int bit = p[l] > (double)Tc[node] ? 1 : 0;
        k = (k << 1) | bit;
        node = 2 * node + 1 + bit;
      }
      codes[(size_t)n * 64 + c] = (uint8_t)k;
    }
  }
}

// ---- k2: out = onehot(codes) @ L^T, fp32 out. BK=64, (256,3) ----
__global__ __launch_bounds__(256, 3) void k2_out(
    const uint8_t* __restrict__ codes, const u16* __restrict__ Lb,
    float* __restrict__ Og) {
  __shared__ __align__(16) u16 Ltile[128 * 64];       // 16KB [m-row][8 slots], XOR
  __shared__ __align__(16) uint8_t codesT[64 * 128];  // [c][n] 8KB
  __shared__ __align__(16) u16 lut[32 * 8];

  const int t = threadIdx.x, mb = blockIdx.x, nb = blockIdx.y;
  const int lane = t & 63, wave = t >> 6, quad = lane >> 4, l16 = lane & 15;
  const int wr = wave >> 1, wc = wave & 1;

  if (t < 32) {  // A-frag LUT: entry (h,v): frag[j] = (v == h*8+j)
    int h = t >> 4, v = t & 15;
#pragma unroll
    for (int j = 0; j < 8; ++j)
      lut[t * 8 + j] = (v == h * 8 + j) ? (u16)0x3F80 : (u16)0;
  }
  {  // codes -> [c][n] transposed in LDS
    int n = t >> 1, part = t & 1;
    const u32* src = (const u32*)(codes + (size_t)(nb * 128 + n) * 64 + part * 32);
#pragma unroll
    for (int i = 0; i < 8; ++i) {
      u32 w = src[i];
      int c4 = part * 32 + i * 4;
      codesT[(c4 + 0) * 128 + n] = (uint8_t)(w & 0xff);
      codesT[(c4 + 1) * 128 + n] = (uint8_t)((w >> 8) & 0xff);
      codesT[(c4 + 2) * 128 + n] = (uint8_t)((w >> 16) & 0xff);
      codesT[(c4 + 3) * 128 + n] = (uint8_t)((w >> 24) & 0xff);
    }
  }

  f32x4 acc[4][4] = {};

  for (int kb = 0; kb < 16; ++kb) {
    __syncthreads();  // first iter: codesT/lut visible; later: prev reads retired
#pragma unroll
    for (int q = 0; q < 4; ++q) {  // 128 rows x 8 slots = 1024 chunks of 16B
      int cid = t + q * 256, r = cid >> 3, s = cid & 7, g = s ^ (r & 7);
      gld_lds16(Lb + (size_t)(mb * 128 + r) * CKDIM + kb * 64 + g * 8,
                Ltile + cid * 8);
    }
    __syncthreads();

#pragma unroll
    for (int ks = 0; ks < 2; ++ks) {
      const int c0 = kb * 4 + ks * 2 + (quad >> 1);
      const int h = quad & 1;
      bf16x8 a[4], b[4];
#pragma unroll
      for (int i = 0; i < 4; ++i) {
        int row = wr * 64 + i * 16 + l16;
        int v = codesT[c0 * 128 + row] & 15;  // defensive mask
        a[i] = *(const bf16x8*)(lut + (h * 16 + v) * 8);
      }
#pragma unroll
      for (int j = 0; j < 4; ++j) {
        int rm = wc * 64 + j * 16 + l16;
        int slot = (ks * 4 + quad) ^ (rm & 7);
        b[j] = *(const bf16x8*)(Ltile + rm * 64 + slot * 8);
      }
      __builtin_amdgcn_s_setprio(1);
#pragma unroll
      for (int i = 0; i < 4; ++i)
#pragma unroll
        for (int j = 0; j < 4; ++j)
          acc[i][j] = __builtin_amdgcn_mfma_f32_16x16x32_bf16(a[i], b[j], acc[i][j], 0, 0, 0);
      __builtin_amdgcn_s_setprio(0);
    }
  }

#pragma unroll
  for (int i = 0; i < 4; ++i)
#pragma unroll
    for (int j = 0; j < 4; ++j) {
      int row = nb * 128 + wr * 64 + i * 16 + quad * 4;
      int col = mb * 128 + wc * 64 + j * 16 + l16;
#pragma unroll
      for (int r = 0; r < 4; ++r)
        Og[(size_t)(row + r) * MOUT + col] = acc[i][j][r];
    }
}

extern "C" void kernel_launch(void* const* d_in, const int* in_sizes, int n_in,
                              void* d_out, int out_size, void* d_ws, size_t ws_size,
                              hipStream_t stream) {
  // inputs (all float32): I (N,512), T (960), L (512,64,16), A (512,256), S, B
  const float* Ig = (const float*)d_in[0];
  const float* Tg = (const float*)d_in[1];
  const float* Lg = (const float*)d_in[2];
  const float* Ag = (const float*)d_in[3];
  float* Og = (float*)d_out;

  char* ws = (char*)d_ws;
  u32* cnt = (u32*)ws;                                 // 4B @ 0
  u32* list = (u32*)(ws + 4096);                       // 4MB flag list
  uint8_t* codes = (uint8_t*)(ws + (8u << 20));        // 2MB @ 8MB
  u16* Ath = (u16*)(ws + (10u << 20));                 // 256KB @ 10MB
  u16* Atl = Ath + 256 * DDIM;                         // 256KB, ADJACENT (k1 relies on it)
  u16* Lbf = (u16*)(ws + (10u << 20) + (512u << 10));  // 1MB

  k0_prep<<<dim3(544), dim3(256), 0, stream>>>(Ag, Ath, Atl, Lg, Lbf, cnt);
  k1_p_codes<<<dim3(512), dim3(256), 0, stream>>>(Ig, Ath, Tg, codes, cnt, list);
  k1b_rescue<<<dim3(512), dim3(256), 0, stream>>>(Ig, Ag, Tg, cnt, list, codes);
  k2_out<<<dim3(4, 256), dim3(256), 0, stream>>>(codes, Lbf, Og);
}

// Round 4
// 213.379 us; speedup vs baseline: 2.4286x; 1.1667x over previous
//
#include <hip/hip_runtime.h>
#include <stdint.h>

// HalutMatmul forward, fp32 in/out, gfx950.
// N=32768, D=512, C=64, K=16, M=512, DEPTH=4, NODES=15.
// R4: k1 occupancy was GRID-limited (512 blocks / 256 CU = 2/CU, 20% measured).
//     k1 tile 64x256 -> 32x256, grid 1024 -> 4 blocks/CU, LDS 36KB, acc[2][4]
//     (32 AGPR; fits the (256,4) 128-reg cap, unlike R2's 168).
// k0_prep: fused A->At hi/lo planes + L->bf16 + cnt=0.
// k1b: wave-per-entry fp64 rescue. k2: onehot@L^T, BK=64, (256,3). Unchanged.

#define DDIM 512
#define CD4 256
#define CKDIM 1024
#define MOUT 512
#define NODES 15
#define CAP (1u << 20)

typedef unsigned short u16;
typedef unsigned int u32;
typedef __attribute__((ext_vector_type(8))) __bf16 bf16x8;
typedef __attribute__((ext_vector_type(4))) float f32x4;
typedef __attribute__((ext_vector_type(4))) u32 u32x4;
typedef __attribute__((ext_vector_type(2))) u32 u32x2;

__device__ __forceinline__ void gld_lds16(const void* g, void* l) {
  __builtin_amdgcn_global_load_lds(
      (const __attribute__((address_space(1))) void*)g,
      (__attribute__((address_space(3))) void*)l, 16, 0, 0);
}
__device__ __forceinline__ float bf2f(u16 u) {
  uint32_t x = ((uint32_t)u) << 16; return __builtin_bit_cast(float, x);
}
__device__ __forceinline__ u16 f2bf(float f) {  // RNE
  uint32_t x = __builtin_bit_cast(uint32_t, f);
  return (u16)((x + 0x7FFFu + ((x >> 16) & 1u)) >> 16);
}

// ---- k0_prep: fused preprocessing, one dispatch ----
// blocks 0..31: A (512x256 f32) -> At hi/lo bf16 planes (256x512), LDS transpose
// blocks 32..543: L (512x1024 f32) -> bf16 plane; block 32 t0 zeroes flagcnt
__global__ __launch_bounds__(256) void k0_prep(const float* __restrict__ Ag,
                                               u16* __restrict__ Ath,
                                               u16* __restrict__ Atl,
                                               const float* __restrict__ Lg,
                                               u16* __restrict__ Lb,
                                               u32* __restrict__ flagcnt) {
  const int bx = blockIdx.x, t = threadIdx.x;
  if (bx < 32) {
    __shared__ float Tl[64][65];  // +1 pad: conflict-free column reads
    const int cx = bx & 3, ky = bx >> 2;
    const int lane = t & 63, w = t >> 6;
#pragma unroll
    for (int rr = 0; rr < 16; ++rr) {  // read: rows coalesced over lanes
      int r = w * 16 + rr;
      Tl[r][lane] = Ag[(size_t)(ky * 64 + r) * CD4 + cx * 64 + lane];
    }
    __syncthreads();
#pragma unroll
    for (int rr = 0; rr < 16; ++rr) {  // write: k coalesced over lanes
      int c = w * 16 + rr;
      float x = Tl[lane][c];
      u16 h = f2bf(x);
      u16 l = f2bf(x - bf2f(h));
      size_t o = (size_t)(cx * 64 + c) * DDIM + ky * 64 + lane;
      Ath[o] = h;
      Atl[o] = l;
    }
  } else {
    if (bx == 32 && t == 0) *flagcnt = 0;
    int i = ((bx - 32) * 256 + t) * 4;
    f32x4 v = *(const f32x4*)(Lg + i);
    u32 lo = (u32)f2bf(v[0]) | ((u32)f2bf(v[1]) << 16);
    u32 hi = (u32)f2bf(v[2]) | ((u32)f2bf(v[3]) << 16);
    *(u32*)(Lb + i) = lo;
    *(u32*)(Lb + i + 2) = hi;
  }
}

// ---- k1: coarse P (hi/lo split MFMA) + tree codes + flags ----
// tile 32 I-rows x 256 P-cols (all 64 codebooks). grid 1024 -> 4 blocks/CU.
// LDS 36KB single-buffer staging (If 4KB + Bt 32KB).
// waves 1x4 over cols: wave w owns cols w*64..w*64+63, acc[2][4].
// Epilogue: per-frag 4x4 lane transpose (shfl_xor) -> descent in registers;
// flags: ballot-compacted per wave in LDS, ONE atomicAdd per block, coalesced flush.
__global__ __launch_bounds__(256, 4) void k1_p_codes(
    const float* __restrict__ Ig, const u16* __restrict__ Ath,
    const float* __restrict__ Tg,
    uint8_t* __restrict__ codes, u32* __restrict__ flagcnt,
    u32* __restrict__ flaglist) {
  __shared__ __align__(16) char smem[36864];
  float* If = (float*)smem;        // 4KB: [32 rows][8 slots]x16B, slot s holds g=s^(r&7)
  u16* Bt = (u16*)(smem + 4096);   // 32KB: [256 rows][8 slots]; g<4 hi plane, g>=4 lo

  const int t = threadIdx.x, nb = blockIdx.x;
  const int lane = t & 63, wave = t >> 6, quad = lane >> 4, l16 = lane & 15;

  f32x4 acc[2][4] = {};

  for (int kb = 0; kb < 16; ++kb) {
    __syncthreads();  // prev iter's ds_reads retired before restage
    {  // I tile: 32 rows x 8 chunk-slots = 256 chunks
      int r = t >> 3, s = t & 7, g = s ^ (r & 7);
      gld_lds16(Ig + (size_t)(nb * 32 + r) * DDIM + kb * 32 + g * 4, If + t * 4);
    }
    // B tile: 256 At-rows x 8 slots; g<4 -> hi plane (k-chunk g), g>=4 -> lo (g-4)
#pragma unroll
    for (int q = 0; q < 8; ++q) {
      int cid = t + q * 256, r = cid >> 3, s = cid & 7, g = s ^ (r & 7);
      gld_lds16(Ath + (size_t)(g >> 2) * (256 * DDIM) +
                    (size_t)r * DDIM + kb * 32 + (g & 3) * 8,
                Bt + cid * 8);
    }
    __syncthreads();  // staged data visible (vmcnt(0) drained by compiler)

    bf16x8 ah[2], al[2], bh[4], bl[4];
#pragma unroll
    for (int i = 0; i < 2; ++i) {
      int ra = i * 16 + l16;
      int s0 = ra * 8 + ((quad * 2) ^ (ra & 7));
      int s1 = ra * 8 + ((quad * 2 + 1) ^ (ra & 7));
      f32x4 c0 = *(const f32x4*)(If + s0 * 4);
      f32x4 c1 = *(const f32x4*)(If + s1 * 4);
      float xs[8] = {c0[0], c0[1], c0[2], c0[3], c1[0], c1[1], c1[2], c1[3]};
      u32 hw[4], lw[4];
#pragma unroll
      for (int p = 0; p < 4; ++p) {  // truncation split: hi = top16 bits, lo = x - hi
        u32 u0 = __builtin_bit_cast(u32, xs[2 * p]);
        u32 u1 = __builtin_bit_cast(u32, xs[2 * p + 1]);
        hw[p] = __builtin_amdgcn_perm(u1, u0, 0x07060302);
        float h0 = __builtin_bit_cast(float, u0 & 0xFFFF0000u);
        float h1 = __builtin_bit_cast(float, u1 & 0xFFFF0000u);
        u32 l0 = __builtin_bit_cast(u32, xs[2 * p] - h0);
        u32 l1 = __builtin_bit_cast(u32, xs[2 * p + 1] - h1);
        lw[p] = __builtin_amdgcn_perm(l1, l0, 0x07060302);
      }
      ah[i] = __builtin_bit_cast(bf16x8, (u32x4){hw[0], hw[1], hw[2], hw[3]});
      al[i] = __builtin_bit_cast(bf16x8, (u32x4){lw[0], lw[1], lw[2], lw[3]});
    }
#pragma unroll
    for (int j = 0; j < 4; ++j) {
      int rb = wave * 64 + j * 16 + l16;
      int sh = quad ^ (rb & 7), sl = (4 + quad) ^ (rb & 7);
      bh[j] = *(const bf16x8*)(Bt + (rb * 8 + sh) * 8);
      bl[j] = *(const bf16x8*)(Bt + (rb * 8 + sl) * 8);
    }
    __builtin_amdgcn_s_setprio(1);
#pragma unroll
    for (int i = 0; i < 2; ++i)
#pragma unroll
      for (int j = 0; j < 4; ++j) {
        acc[i][j] = __builtin_amdgcn_mfma_f32_16x16x32_bf16(ah[i], bh[j], acc[i][j], 0, 0, 0);
        acc[i][j] = __builtin_amdgcn_mfma_f32_16x16x32_bf16(ah[i], bl[j], acc[i][j], 0, 0, 0);
        acc[i][j] = __builtin_amdgcn_mfma_f32_16x16x32_bf16(al[i], bh[j], acc[i][j], 0, 0, 0);
      }
    __builtin_amdgcn_s_setprio(0);
  }

  __syncthreads();  // last iter's LDS reads done; reuse smem
  float* Tl = (float*)smem;                      // 3.84KB thresholds
  uint8_t* codes_lds = (uint8_t*)(smem + 4096);  // [32 rows][64 c] 2KB
  u32* flagbuf = (u32*)(smem + 8192);            // [4 waves][512] 8KB
  u32* fmeta = (u32*)(smem + 16384);             // wave counts + base
  if (t < 240) *(f32x4*)(Tl + t * 4) = *(const f32x4*)(Tg + t * 4);
  __syncthreads();

  // Epilogue: MFMA C layout per lane = 4 rows (regs) x 1 col (l16).
  // col = c*4 + level, so lanes 4c..4c+3 of a quad hold levels 0..3 of codebook c.
  // 4x4 lane transpose (xor1, xor2) -> lane m = l16&3 holds row m's 4 levels.
  u32 wcnt = 0;  // wave-uniform running flag count
#pragma unroll
  for (int i = 0; i < 2; ++i)
#pragma unroll
    for (int j = 0; j < 4; ++j) {
      f32x4 v = acc[i][j];
      {
        float x = (l16 & 1) ? v[0] : v[1];
        float y = (l16 & 1) ? v[2] : v[3];
        x = __shfl_xor(x, 1);
        y = __shfl_xor(y, 1);
        if (l16 & 1) { v[0] = x; v[2] = y; } else { v[1] = x; v[3] = y; }
        float p = (l16 & 2) ? v[0] : v[2];
        float q = (l16 & 2) ? v[1] : v[3];
        p = __shfl_xor(p, 2);
        q = __shfl_xor(q, 2);
        if (l16 & 2) { v[0] = p; v[1] = q; } else { v[2] = p; v[3] = q; }
      }
      int row = i * 16 + quad * 4 + (l16 & 3);
      int cg = wave * 16 + j * 4 + (l16 >> 2);
      const float* Tc = Tl + cg * NODES;
      int node = 0, k = 0;
      float mm = 1e30f;
#pragma unroll
      for (int l = 0; l < 4; ++l) {
        float h = v[l] - Tc[node];
        mm = fminf(mm, __builtin_fabsf(h));
        int bit = h > 0.0f ? 1 : 0;
        k = (k << 1) | bit;
        node = 2 * node + 1 + bit;
      }
      codes_lds[row * 64 + cg] = (uint8_t)k;
      // coarse error ~1e-4 << tau: unflagged codes are exact. Ballot-compact.
      bool fl = mm < 2e-3f;
      unsigned long long bm = __ballot(fl);
      if (bm) {
        if (fl) {
          int rank = __popcll(bm & ((1ull << lane) - 1ull));
          flagbuf[wave * 512 + wcnt + rank] =
              ((u32)(nb * 32 + row) << 6) | (u32)cg;
        }
        wcnt += (u32)__popcll(bm);
      }
    }
  if (lane == 0) fmeta[wave] = wcnt;
  __syncthreads();
  {
    u32 c0 = fmeta[0], c1 = fmeta[1], c2 = fmeta[2], c3 = fmeta[3];
    u32 total = c0 + c1 + c2 + c3;
    if (t == 0 && total) fmeta[4] = atomicAdd(flagcnt, total);
    // coalesced codes write: 256 threads x 8B = 2KB tile
    *(u32x2*)(codes + (size_t)nb * 2048 + t * 8) =
        *(const u32x2*)(codes_lds + t * 8);
    __syncthreads();
    if (total) {
      u32 base = fmeta[4];
      u32 pre = (wave > 0 ? c0 : 0) + (wave > 1 ? c1 : 0) + (wave > 2 ? c2 : 0);
      u32 mycnt = fmeta[wave];
      for (u32 i2 = (u32)lane; i2 < mycnt; i2 += 64) {
        u32 pos = base + pre + i2;
        if (pos < CAP) flaglist[pos] = flagbuf[wave * 512 + i2];
      }
    }
  }
}

// ---- k1b: fp64 rescue, one WAVE per flagged entry ----
// lanes split the 512 dims (coalesced I reads), butterfly fp64 reduce, lane 0 descends.
__global__ __launch_bounds__(256) void k1b_rescue(
    const float* __restrict__ Ig, const float* __restrict__ Ag,
    const float* __restrict__ Tg, const u32* __restrict__ cnt,
    const u32* __restrict__ list, uint8_t* __restrict__ codes) {
  u32 total = *cnt;
  if (total > CAP) total = CAP;
  const int lane = threadIdx.x & 63;
  const u32 wid = (u32)((blockIdx.x * blockDim.x + threadIdx.x) >> 6);
  const u32 nw = (u32)((gridDim.x * blockDim.x) >> 6);
  for (u32 e = wid; e < total; e += nw) {
    u32 v = list[e];
    int n = v >> 6, c = v & 63;
    const float* Ir = Ig + (size_t)n * DDIM;
    const float* Ac = Ag + c * 4;
    double p0 = 0.0, p1 = 0.0, p2 = 0.0, p3 = 0.0;
#pragma unroll
    for (int u = 0; u < 8; ++u) {
      int d = u * 64 + lane;
      double iv = (double)Ir[d];
      f32x4 a = *(const f32x4*)(Ac + (size_t)d * CD4);
      p0 += iv * (double)a[0]; p1 += iv * (double)a[1];
      p2 += iv * (double)a[2]; p3 += iv * (double)a[3];
    }
#pragma unroll
    for (int off = 32; off; off >>= 1) {
      p0 += __shfl_xor(p0, off);
      p1 += __shfl_xor(p1, off);
      p2 += __shfl_xor(p2, off);
      p3 += __shfl_xor(p3, off);
    }
    if (lane == 0) {
      double p[4] = {p0, p1, p2, p3};
      const float* Tc = Tg + c * NODES;
      int node = 0, k = 0;
      for (int l = 0; l < 4; ++l) {
        int bit = p[l] > (double)Tc[node] ? 1 : 0;
        k = (k << 1) | bit;
        node = 2 * node + 1 + bit;
      }
      codes[(size_t)n * 64 + c] = (uint8_t)k;
    }
  }
}

// ---- k2: out = onehot(codes) @ L^T, fp32 out. BK=64, (256,3) ----
__global__ __launch_bounds__(256, 3) void k2_out(
    const uint8_t* __restrict__ codes, const u16* __restrict__ Lb,
    float* __restrict__ Og) {
  __shared__ __align__(16) u16 Ltile[128 * 64];       // 16KB [m-row][8 slots], XOR
  __shared__ __align__(16) uint8_t codesT[64 * 128];  // [c][n] 8KB
  __shared__ __align__(16) u16 lut[32 * 8];

  const int t = threadIdx.x, mb = blockIdx.x, nb = blockIdx.y;
  const int lane = t & 63, wave = t >> 6, quad = lane >> 4, l16 = lane & 15;
  const int wr = wave >> 1, wc = wave & 1;

  if (t < 32) {  // A-frag LUT: entry (h,v): frag[j] = (v == h*8+j)
    int h = t >> 4, v = t & 15;
#pragma unroll
    for (int j = 0; j < 8; ++j)
      lut[t * 8 + j] = (v == h * 8 + j) ? (u16)0x3F80 : (u16)0;
  }
  {  // codes -> [c][n] transposed in LDS
    int n = t >> 1, part = t & 1;
    const u32* src = (const u32*)(codes + (size_t)(nb * 128 + n) * 64 + part * 32);
#pragma unroll
    for (int i = 0; i < 8; ++i) {
      u32 w = src[i];
      int c4 = part * 32 + i * 4;
      codesT[(c4 + 0) * 128 + n] = (uint8_t)(w & 0xff);
      codesT[(c4 + 1) * 128 + n] = (uint8_t)((w >> 8) & 0xff);
      codesT[(c4 + 2) * 128 + n] = (uint8_t)((w >> 16) & 0xff);
      codesT[(c4 + 3) * 128 + n] = (uint8_t)((w >> 24) & 0xff);
    }
  }

  f32x4 acc[4][4] = {};

  for (int kb = 0; kb < 16; ++kb) {
    __syncthreads();  // first iter: codesT/lut visible; later: prev reads retired
#pragma unroll
    for (int q = 0; q < 4; ++q) {  // 128 rows x 8 slots = 1024 chunks of 16B
      int cid = t + q * 256, r = cid >> 3, s = cid & 7, g = s ^ (r & 7);
      gld_lds16(Lb + (size_t)(mb * 128 + r) * CKDIM + kb * 64 + g * 8,
                Ltile + cid * 8);
    }
    __syncthreads();

#pragma unroll
    for (int ks = 0; ks < 2; ++ks) {
      const int c0 = kb * 4 + ks * 2 + (quad >> 1);
      const int h = quad & 1;
      bf16x8 a[4], b[4];
#pragma unroll
      for (int i = 0; i < 4; ++i) {
        int row = wr * 64 + i * 16 + l16;
        int v = codesT[c0 * 128 + row] & 15;  // defensive mask
        a[i] = *(const bf16x8*)(lut + (h * 16 + v) * 8);
      }
#pragma unroll
      for (int j = 0; j < 4; ++j) {
        int rm = wc * 64 + j * 16 + l16;
        int slot = (ks * 4 + quad) ^ (rm & 7);
        b[j] = *(const bf16x8*)(Ltile + rm * 64 + slot * 8);
      }
      __builtin_amdgcn_s_setprio(1);
#pragma unroll
      for (int i = 0; i < 4; ++i)
#pragma unroll
        for (int j = 0; j < 4; ++j)
          acc[i][j] = __builtin_amdgcn_mfma_f32_16x16x32_bf16(a[i], b[j], acc[i][j], 0, 0, 0);
      __builtin_amdgcn_s_setprio(0);
    }
  }

#pragma unroll
  for (int i = 0; i < 4; ++i)
#pragma unroll
    for (int j = 0; j < 4; ++j) {
      int row = nb * 128 + wr * 64 + i * 16 + quad * 4;
      int col = mb * 128 + wc * 64 + j * 16 + l16;
#pragma unroll
      for (int r = 0; r < 4; ++r)
        Og[(size_t)(row + r) * MOUT + col] = acc[i][j][r];
    }
}

extern "C" void kernel_launch(void* const* d_in, const int* in_sizes, int n_in,
                              void* d_out, int out_size, void* d_ws, size_t ws_size,
                              hipStream_t stream) {
  // inputs (all float32): I (N,512), T (960), L (512,64,16), A (512,256), S, B
  const float* Ig = (const float*)d_in[0];
  const float* Tg = (const float*)d_in[1];
  const float* Lg = (const float*)d_in[2];
  const float* Ag = (const float*)d_in[3];
  float* Og = (float*)d_out;

  char* ws = (char*)d_ws;
  u32* cnt = (u32*)ws;                                 // 4B @ 0
  u32* list = (u32*)(ws + 4096);                       // 4MB flag list
  uint8_t* codes = (uint8_t*)(ws + (8u << 20));        // 2MB @ 8MB
  u16* Ath = (u16*)(ws + (10u << 20));                 // 256KB @ 10MB
  u16* Atl = Ath + 256 * DDIM;                         // 256KB, ADJACENT (k1 relies on it)
  u16* Lbf = (u16*)(ws + (10u << 20) + (512u << 10));  // 1MB

  k0_prep<<<dim3(544), dim3(256), 0, stream>>>(Ag, Ath, Atl, Lg, Lbf, cnt);
  k1_p_codes<<<dim3(1024), dim3(256), 0, stream>>>(Ig, Ath, Tg, codes, cnt, list);
  k1b_rescue<<<dim3(512), dim3(256), 0, stream>>>(Ig, Ag, Tg, cnt, list, codes);
  k2_out<<<dim3(4, 256), dim3(256), 0, stream>>>(codes, Lbf, Og);
}